// Round 7
// baseline (246.809 us; speedup 1.0000x reference)
//
#include <hip/hip_runtime.h>
#include <hip/hip_bf16.h>

// ChannelDense: y[b,n,o] = tanh( sum_i x[b,n,i]*W[c[n],o,i] + bias[c[n],o] ) + x[b,n,o]
// B=128, N=2048, IN=OUT=256, 64 channels.
//
// R7: phase-staggering via many small independent wgs.
//  k0 sort: counting-sort by channel; perm packs (c<<16)|n; channels passthrough.
//  k1 wconv: W f32 -> bf16 linear image [c][o][k] in d_ws.
//  k2 main: grid 8192 = (sorted point) x (32-row quarter), XCD-chunked. wg = 256 thr
//    = 4 waves; wave wv owns a 64-wide o-strip. W fragments read DIRECTLY from the
//    bf16 global image per kt (L2-hot: sorted channels + 4 consecutive quarters share
//    the same point/W slice). LDS = one 16KB x quarter-tile ([slab=8][r=32][64B],
//    swizzle ^((r&7)<<4)^((slab&3)<<4) -- the slab XOR kills R6's 8-way A-stage
//    write conflict). One barrier per wg. launch_bounds(256,6) -> 6 wgs/CU resident,
//    independent phases keep HBM fed.

#define N_SZ 2048

typedef __attribute__((ext_vector_type(8))) __bf16 bf16x8;
typedef __attribute__((ext_vector_type(4))) float  f32x4;

__device__ __forceinline__ float bf2f(unsigned u16) {
    union { unsigned u; float f; } v; v.u = u16 << 16;
    return v.f;
}
__device__ __forceinline__ float tanh_fast(float s) {
    float a = fabsf(s);
    float t = __expf(-2.0f * a);
    float r = (1.0f - t) * __builtin_amdgcn_rcpf(1.0f + t);
    return __builtin_copysignf(r, s);
}
__device__ __forceinline__ bf16x8 cvt8(float4 a, float4 b) {
    bf16x8 v;
    v[0] = (__bf16)a.x; v[1] = (__bf16)a.y; v[2] = (__bf16)a.z; v[3] = (__bf16)a.w;
    v[4] = (__bf16)b.x; v[5] = (__bf16)b.y; v[6] = (__bf16)b.z; v[7] = (__bf16)b.w;
    return v;
}

// ---- k0: counting sort; perm[p] = (c<<16)|n; channels passthrough ----
__global__ __launch_bounds__(1024) void sort_kernel(const int* __restrict__ channels,
                                                    int* __restrict__ perm,
                                                    float* __restrict__ out_ch) {
    __shared__ int cnt[64], off[64];
    const int t = threadIdx.x;
    if (t < 64) cnt[t] = 0;
    __syncthreads();
    const int n0 = t, n1 = t + 1024;
    const int c0 = channels[n0], c1 = channels[n1];
    atomicAdd(&cnt[c0], 1);
    atomicAdd(&cnt[c1], 1);
    out_ch[n0] = (float)c0;
    out_ch[n1] = (float)c1;
    __syncthreads();
    if (t == 0) { int s = 0; for (int i = 0; i < 64; ++i) { off[i] = s; s += cnt[i]; } }
    __syncthreads();
    int p0 = atomicAdd(&off[c0], 1); perm[p0] = n0 | (c0 << 16);
    int p1 = atomicAdd(&off[c1], 1); perm[p1] = n1 | (c1 << 16);
}

// ---- k1: W f32 -> bf16 linear image ----
__global__ __launch_bounds__(256) void wconv_kernel(const float* __restrict__ w,
                                                    unsigned short* __restrict__ wsW) {
    const size_t t = (size_t)blockIdx.x * 256 + threadIdx.x;   // 524288 chunks of 8
    const float* src = w + t * 8;
    float4 f0 = *(const float4*)(src);
    float4 f1 = *(const float4*)(src + 4);
    bf16x8 v = cvt8(f0, f1);
    *(bf16x8*)(wsW + t * 8) = v;
}

// ---- k2: main ----
__global__ __launch_bounds__(256, 6) void channel_dense_kernel(
    const float* __restrict__ x, const int* __restrict__ perm,
    const unsigned short* __restrict__ wsW, const float* __restrict__ bias,
    float* __restrict__ y)
{
    __shared__ __align__(16) unsigned char sA[16384];   // [slab=8][r=32][64B]

    const int g  = blockIdx.x;
    const int lg = (g & 7) * 1024 + (g >> 3);           // XCD-chunked over sorted order
    const int pv = perm[lg >> 2];
    const int n  = pv & 0xffff;
    const int c  = pv >> 16;
    const int quarter = lg & 3;                          // rows quarter*32 .. +32
    const int tid = threadIdx.x;

    // ---- A-stage: x[quarter*32 .. +32, n, :] -> bf16 LDS, staged once ----
    {
        const int r = tid >> 3;            // local row 0..31
        const int q = tid & 7;             // k-chunk = slab 0..7
        const float* xr = x + ((size_t)(quarter * 32 + r) * N_SZ + n) * 256 + q * 32;
        float4 la[8];
        #pragma unroll
        for (int j = 0; j < 8; ++j) la[j] = *(const float4*)(xr + j * 4);
        const int swz = ((r & 7) << 4) ^ ((q & 3) << 4);
        #pragma unroll
        for (int j = 0; j < 4; ++j) {
            bf16x8 v = cvt8(la[2 * j], la[2 * j + 1]);
            *(bf16x8*)(sA + q * 2048 + ((r * 64 + j * 16) ^ swz)) = v;
        }
    }
    __syncthreads();                       // the ONLY barrier

    const int lane = tid & 63, wv = tid >> 6;            // wv 0..3
    const int lr   = lane & 15, lg4 = lane >> 4;

    // W fragment base: W[c][wv*64 + mo*16 + lr][kt*32 + lg4*8 ..+8]
    const unsigned short* wrow = wsW + (((size_t)c * 256 + wv * 64 + lr) << 8) + lg4 * 8;
    const int lanebyte = (lr * 64 + lg4 * 16) ^ ((lr & 7) << 4);

    f32x4 acc[4][2] = {};

    #pragma unroll
    for (int kt = 0; kt < 8; ++kt) {
        bf16x8 wf[4];
        #pragma unroll
        for (int mo = 0; mo < 4; ++mo)
            wf[mo] = *(const bf16x8*)(wrow + mo * 4096 + kt * 32);
        bf16x8 xf[2];
        const int lb = lanebyte ^ ((kt & 3) << 4);
        xf[0] = *(const bf16x8*)(sA + kt * 2048 + lb);
        xf[1] = *(const bf16x8*)(sA + kt * 2048 + 1024 + lb);
        #pragma unroll
        for (int mo = 0; mo < 4; ++mo) {
            acc[mo][0] = __builtin_amdgcn_mfma_f32_16x16x32_bf16(wf[mo], xf[0], acc[mo][0], 0, 0, 0);
            acc[mo][1] = __builtin_amdgcn_mfma_f32_16x16x32_bf16(wf[mo], xf[1], acc[mo][1], 0, 0, 0);
        }
    }

    // ---- epilogue: bias + tanh + residual(LDS bf16) + float4 stores ----
    #pragma unroll
    for (int mo = 0; mo < 4; ++mo) {
        const int o0 = wv * 64 + mo * 16 + lg4 * 4;      // 4 consecutive o
        const float4 bv = *(const float4*)(bias + c * 256 + o0);
        const int s     = o0 >> 5;                        // residual slab
        const int intra = (o0 & 31) * 2;
        #pragma unroll
        for (int nb = 0; nb < 2; ++nb) {
            const int rl = nb * 16 + lr;                 // local row
            const int b  = quarter * 32 + rl;
            const int rbyte = s * 2048 +
                ((rl * 64 + intra) ^ ((rl & 7) << 4) ^ ((s & 3) << 4));
            uint2 rv = *(const uint2*)(sA + rbyte);
            float4 o;
            o.x = tanh_fast(acc[mo][nb][0] + bv.x) + bf2f(rv.x & 0xffffu);
            o.y = tanh_fast(acc[mo][nb][1] + bv.y) + bf2f(rv.x >> 16);
            o.z = tanh_fast(acc[mo][nb][2] + bv.z) + bf2f(rv.y & 0xffffu);
            o.w = tanh_fast(acc[mo][nb][3] + bv.w) + bf2f(rv.y >> 16);
            *(float4*)(y + ((size_t)b * N_SZ + n) * 256 + o0) = o;
        }
    }
}

extern "C" void kernel_launch(void* const* d_in, const int* in_sizes, int n_in,
                              void* d_out, int out_size, void* d_ws, size_t ws_size,
                              hipStream_t stream) {
    const float* x        = (const float*)d_in[0];
    const int*   channels = (const int*)d_in[1];
    const float* weight   = (const float*)d_in[2];
    const float* bias     = (const float*)d_in[3];
    float* y = (float*)d_out;

    unsigned short* wsW = (unsigned short*)d_ws;             // 8 MB bf16 W image
    int* perm = (int*)((unsigned char*)d_ws + (64u << 17));  // + 8KB perm

    sort_kernel<<<dim3(1), dim3(1024), 0, stream>>>(
        channels, perm, y + (size_t)128 * N_SZ * 256);
    wconv_kernel<<<dim3(2048), dim3(256), 0, stream>>>(weight, wsW);
    channel_dense_kernel<<<dim3(8192), dim3(256), 0, stream>>>(
        x, perm, wsW, bias, y);
}

// Round 8
// 181.818 us; speedup vs baseline: 1.3575x; 1.3575x over previous
//
#include <hip/hip_runtime.h>
#include <hip/hip_bf16.h>

// ChannelDense: y[b,n,o] = tanh( sum_i x[b,n,i]*W[c[n],o,i] + bias[c[n],o] ) + x[b,n,o]
// B=128, N=2048, IN=OUT=256, 64 channels.
//
// R8: W-stationary-in-registers, balanced sorted chunks.
//  k0 sort: counting-sort by channel; perm packs (c<<16)|n; channels passthrough.
//  k1 wconv: W f32 -> bf16 linear image [c][o][k] in d_ws.
//  k2 main: 512 wgs = 128 chunks (16 sorted points each, exact balance) x 4
//    b-quarters, XCD-chunked (a channel's wgs share one XCD L2). wg = 512 thr =
//    8 waves; wave owns a 32-wide o-strip with W IN REGISTERS (wreg[2][8] = 64
//    VGPR), reloaded only on channel change (~1-2x per wg). Per point: x quarter
//    (32 b x 256 k) in a 2x16KB LDS double buffer; kt-loop = pure LDS reads +
//    reg MFMAs (no global in compute path); stage_write(p+1) + issue loads(p+2)
//    BEFORE the tanh epilogue (epilogue covers load latency before the barrier
//    drain); ONE barrier per point. 2 wgs/CU.

#define N_SZ 2048

typedef __attribute__((ext_vector_type(8))) __bf16 bf16x8;
typedef __attribute__((ext_vector_type(4))) float  f32x4;

__device__ __forceinline__ float bf2f(unsigned u16) {
    union { unsigned u; float f; } v; v.u = u16 << 16;
    return v.f;
}
__device__ __forceinline__ float tanh_fast(float s) {
    float a = fabsf(s);
    float t = __expf(-2.0f * a);
    float r = (1.0f - t) * __builtin_amdgcn_rcpf(1.0f + t);
    return __builtin_copysignf(r, s);
}
__device__ __forceinline__ bf16x8 cvt8(float4 a, float4 b) {
    bf16x8 v;
    v[0] = (__bf16)a.x; v[1] = (__bf16)a.y; v[2] = (__bf16)a.z; v[3] = (__bf16)a.w;
    v[4] = (__bf16)b.x; v[5] = (__bf16)b.y; v[6] = (__bf16)b.z; v[7] = (__bf16)b.w;
    return v;
}

// ---- k0: counting sort; perm[p] = (c<<16)|n; channels passthrough ----
__global__ __launch_bounds__(1024) void sort_kernel(const int* __restrict__ channels,
                                                    int* __restrict__ perm,
                                                    float* __restrict__ out_ch) {
    __shared__ int cnt[64], off[64];
    const int t = threadIdx.x;
    if (t < 64) cnt[t] = 0;
    __syncthreads();
    const int n0 = t, n1 = t + 1024;
    const int c0 = channels[n0], c1 = channels[n1];
    atomicAdd(&cnt[c0], 1);
    atomicAdd(&cnt[c1], 1);
    out_ch[n0] = (float)c0;
    out_ch[n1] = (float)c1;
    __syncthreads();
    if (t == 0) { int s = 0; for (int i = 0; i < 64; ++i) { off[i] = s; s += cnt[i]; } }
    __syncthreads();
    int p0 = atomicAdd(&off[c0], 1); perm[p0] = n0 | (c0 << 16);
    int p1 = atomicAdd(&off[c1], 1); perm[p1] = n1 | (c1 << 16);
}

// ---- k1: W f32 -> bf16 linear image ----
__global__ __launch_bounds__(256) void wconv_kernel(const float* __restrict__ w,
                                                    unsigned short* __restrict__ wsW) {
    const size_t t = (size_t)blockIdx.x * 256 + threadIdx.x;   // 524288 chunks of 8
    const float* src = w + t * 8;
    float4 f0 = *(const float4*)(src);
    float4 f1 = *(const float4*)(src + 4);
    bf16x8 v = cvt8(f0, f1);
    *(bf16x8*)(wsW + t * 8) = v;
}

// ---- k2: main ----
__global__ __launch_bounds__(512, 4) void channel_dense_kernel(
    const float* __restrict__ x, const int* __restrict__ perm,
    const unsigned short* __restrict__ wsW, const float* __restrict__ bias,
    float* __restrict__ y)
{
    __shared__ __align__(16) unsigned char sA[2][16384];  // [slab=8][r=32][64B] each

    const int g  = blockIdx.x;                 // 0..511
    const int lg = (g & 7) * 64 + (g >> 3);    // XCD-chunked: XCD gets 16 chunks
    const int chunk   = lg >> 2;               // 0..127 -> points [chunk*16, +16)
    const int quarter = lg & 3;                // b rows quarter*32 .. +32
    const int tid  = threadIdx.x;
    const int lane = tid & 63, wv = tid >> 6;  // 8 waves
    const int lr   = lane & 15, lg4 = lane >> 4;

    // --- staging mapping: thread = (row sr 0..31, k-chunk sh 0..15 of 16 floats) ---
    const int sr = tid >> 4;
    const int sh = tid & 15;
    const int s_slab = sh >> 1;
    const int s_lin0 = sr * 64 + (sh & 1) * 32;
    const int s_swz  = ((sr & 7) << 4) ^ ((s_slab & 3) << 4);
    const int s_addr0 = s_slab * 2048 + ((s_lin0)      ^ s_swz);
    const int s_addr1 = s_slab * 2048 + ((s_lin0 + 16) ^ s_swz);

    float4 la0, la1, la2, la3;                 // 16 floats: x[row][sh*16 .. +16]
    auto stage_load = [&](int n_) {
        const float* p = x + ((size_t)(quarter * 32 + sr) * N_SZ + n_) * 256 + sh * 16;
        la0 = *(const float4*)(p);     la1 = *(const float4*)(p + 4);
        la2 = *(const float4*)(p + 8); la3 = *(const float4*)(p + 12);
    };
    auto stage_write = [&](int buf) {
        *(bf16x8*)(&sA[buf][s_addr0]) = cvt8(la0, la1);
        *(bf16x8*)(&sA[buf][s_addr1]) = cvt8(la2, la3);
    };

    const int p0 = chunk * 16;

    // prologue: point 0 -> LDS buf0; point 1 -> regs
    int pv_cur = perm[p0];
    stage_load(pv_cur & 0xffff);
    stage_write(0);
    int pv_nxt = perm[p0 + 1];
    stage_load(pv_nxt & 0xffff);
    __syncthreads();

    bf16x8 wreg[2][8];                         // W[c][wv*32 + {0,16}+lr][.]
    float4 bv0, bv1;
    int c_cur = -1;
    int cur = 0;
    const int o0 = wv * 32 + lg4 * 4;          // epilogue o base (mo=0)

    for (int i = 0; i < 16; ++i) {
        const int n = pv_cur & 0xffff;
        const int c = pv_cur >> 16;
        if (c != c_cur) {                      // wg-uniform branch
            c_cur = c;
            const unsigned short* wl = wsW + (((size_t)c * 256 + wv * 32 + lr) << 8) + lg4 * 8;
            #pragma unroll
            for (int kt = 0; kt < 8; ++kt) {
                wreg[0][kt] = *(const bf16x8*)(wl + kt * 32);
                wreg[1][kt] = *(const bf16x8*)(wl + 16 * 256 + kt * 32);
            }
            bv0 = *(const float4*)(bias + c * 256 + o0);
            bv1 = *(const float4*)(bias + c * 256 + o0 + 16);
        }

        // ---- compute: 16 ds_read_b128 + 32 MFMA, all operands reg/LDS ----
        f32x4 acc[2][2] = {};
        #pragma unroll
        for (int kt = 0; kt < 8; ++kt) {
            const int lb = (lr * 64 + lg4 * 16) ^ ((lr & 7) << 4) ^ ((kt & 3) << 4);
            bf16x8 xf0 = *(const bf16x8*)(&sA[cur][kt * 2048 + lb]);
            bf16x8 xf1 = *(const bf16x8*)(&sA[cur][kt * 2048 + 1024 + lb]);
            acc[0][0] = __builtin_amdgcn_mfma_f32_16x16x32_bf16(wreg[0][kt], xf0, acc[0][0], 0, 0, 0);
            acc[0][1] = __builtin_amdgcn_mfma_f32_16x16x32_bf16(wreg[0][kt], xf1, acc[0][1], 0, 0, 0);
            acc[1][0] = __builtin_amdgcn_mfma_f32_16x16x32_bf16(wreg[1][kt], xf0, acc[1][0], 0, 0, 0);
            acc[1][1] = __builtin_amdgcn_mfma_f32_16x16x32_bf16(wreg[1][kt], xf1, acc[1][1], 0, 0, 0);
        }

        // ---- staging for the pipeline BEFORE the epilogue (tanh covers latency) ----
        if (i < 15) {
            stage_write(cur ^ 1);              // la holds point p+1 (loaded long ago)
            if (i < 14) {
                pv_cur = pv_nxt;
                pv_nxt = perm[p0 + i + 2];
                stage_load(pv_nxt & 0xffff);   // lands during epilogue
            } else {
                pv_cur = pv_nxt;
            }
        }

        // ---- epilogue: bias + tanh + residual(LDS) + float4 stores ----
        #pragma unroll
        for (int mo = 0; mo < 2; ++mo) {
            const float4 bv = mo ? bv1 : bv0;
            const int oo    = o0 + mo * 16;
            const int s     = oo >> 5;
            const int intra = (oo & 31) * 2;
            #pragma unroll
            for (int nb = 0; nb < 2; ++nb) {
                const int rl = nb * 16 + lr;
                const int b  = quarter * 32 + rl;
                const int rbyte = s * 2048 +
                    ((rl * 64 + intra) ^ ((rl & 7) << 4) ^ ((s & 3) << 4));
                uint2 rv = *(const uint2*)(&sA[cur][rbyte]);
                float4 o;
                o.x = tanh_fast(acc[mo][nb][0] + bv.x) + bf2f(rv.x & 0xffffu);
                o.y = tanh_fast(acc[mo][nb][1] + bv.y) + bf2f(rv.x >> 16);
                o.z = tanh_fast(acc[mo][nb][2] + bv.z) + bf2f(rv.y & 0xffffu);
                o.w = tanh_fast(acc[mo][nb][3] + bv.w) + bf2f(rv.y >> 16);
                *(float4*)(y + ((size_t)b * N_SZ + n) * 256 + oo) = o;
            }
        }

        if (i < 15) __syncthreads();
        cur ^= 1;
    }
}

extern "C" void kernel_launch(void* const* d_in, const int* in_sizes, int n_in,
                              void* d_out, int out_size, void* d_ws, size_t ws_size,
                              hipStream_t stream) {
    const float* x        = (const float*)d_in[0];
    const int*   channels = (const int*)d_in[1];
    const float* weight   = (const float*)d_in[2];
    const float* bias     = (const float*)d_in[3];
    float* y = (float*)d_out;

    unsigned short* wsW = (unsigned short*)d_ws;             // 8 MB bf16 W image
    int* perm = (int*)((unsigned char*)d_ws + (64u << 17));  // + 8KB perm

    sort_kernel<<<dim3(1), dim3(1024), 0, stream>>>(
        channels, perm, y + (size_t)128 * N_SZ * 256);
    wconv_kernel<<<dim3(2048), dim3(256), 0, stream>>>(weight, wsW);
    channel_dense_kernel<<<dim3(512), dim3(512), 0, stream>>>(
        x, perm, wsW, bias, y);
}